// Round 1
// baseline (50001.822 us; speedup 1.0000x reference)
//
#include <hip/hip_runtime.h>
#include <hip/hip_cooperative_groups.h>
#include <math.h>

namespace cg = cooperative_groups;

typedef __attribute__((ext_vector_type(4))) float f32x4;
typedef __attribute__((ext_vector_type(8))) short bfrag8;   // 8 bf16 = 4 VGPRs

// ---- ws layout (bytes) ----
// wre_hi: 5 mats * 1024 * 256 * 2B = 2621440
// wre_lo: same                      @ 2621440
// hb_hi : 2 par * 3 layers * 256*256 * 2B = 786432  @ 5242880
// hb_lo : same                      @ 6029312
// total 6815744
#define WRE_LO_OFF 2621440
#define HB_HI_OFF  5242880
#define HB_LO_OFF  6029312

__device__ __forceinline__ unsigned short f2bf(float f){
  union { float f; unsigned u; } x; x.f = f;
  unsigned r = x.u + 0x7FFFu + ((x.u >> 16) & 1u);   // RNE
  return (unsigned short)(r >> 16);
}
__device__ __forceinline__ float bf2f(unsigned short s){
  union { unsigned u; float f; } x; x.u = ((unsigned)s) << 16; return x.f;
}

// Reorder the 5 big weight mats into per-(nt)-contiguous rows, split bf16 hi/lo.
// dest row d in [0,1024): nt=d>>6, g=(d>>4)&3, n=d&15 ; src row = g*256 + nt*16 + n
__global__ void init_reorder(const float* __restrict__ hh0, const float* __restrict__ ih1,
                             const float* __restrict__ hh1, const float* __restrict__ ih2,
                             const float* __restrict__ hh2,
                             unsigned short* __restrict__ wre_hi,
                             unsigned short* __restrict__ wre_lo){
  int e = blockIdx.x * 256 + threadIdx.x;        // 5*2^18 total
  int mat = e >> 18;
  int d   = (e >> 8) & 1023;
  int k   = e & 255;
  int nt = d >> 6, g = (d >> 4) & 3, n = d & 15;
  int src_row = g*256 + nt*16 + n;
  const float* W = (mat==0) ? hh0 : (mat==1) ? ih1 : (mat==2) ? hh1 : (mat==3) ? ih2 : hh2;
  float v = W[src_row*256 + k];
  unsigned short hi = f2bf(v);
  float lo = v - bf2f(hi);
  wre_hi[e] = hi;
  wre_lo[e] = f2bf(lo);
}

__global__ void init_zero(uint4* __restrict__ p){
  int i = blockIdx.x * 256 + threadIdx.x;        // 384*256 = 98304 * 16B = 1572864 B
  p[i] = make_uint4(0u,0u,0u,0u);
}

__global__ void lstm_coop(
    const float* __restrict__ tracks,
    const float* __restrict__ wih0,
    const float* __restrict__ bih0, const float* __restrict__ bhh0,
    const float* __restrict__ bih1, const float* __restrict__ bhh1,
    const float* __restrict__ bih2, const float* __restrict__ bhh2,
    const unsigned short* __restrict__ wre_hi, const unsigned short* __restrict__ wre_lo,
    unsigned short* __restrict__ hb_hi, unsigned short* __restrict__ hb_lo)
{
  cg::grid_group grid = cg::this_grid();
  const int tid  = threadIdx.x;
  const int nt   = blockIdx.x & 15, bt = blockIdx.x >> 4;
  const int b0   = bt * 16, n0 = nt * 16;
  const int wave = tid >> 6, lane = tid & 63;
  const int m    = lane & 15, quad = lane >> 4;
  const int ub   = tid >> 4, un = tid & 15;     // cell-update ownership: (batch ub, hidden un)

  __shared__ unsigned short hs_hi[16][264], hs_lo[16][264];   // h tile, pad 8 (stride=132 dw == 4 banks)
  __shared__ unsigned short wc_hi[64][136], wc_lo[64][136];   // W chunk (64 rows x 128 k)
  __shared__ float gates_s[4][16][17];

  // per-thread persistent: bias sums, wih0 cols, cell state (exact fp32)
  float bsum[3][4], wx0[4], wx1[4];
  #pragma unroll
  for (int g = 0; g < 4; ++g){
    int r = g*256 + n0 + un;
    bsum[0][g] = bih0[r] + bhh0[r];
    bsum[1][g] = bih1[r] + bhh1[r];
    bsum[2][g] = bih2[r] + bhh2[r];
    wx0[g] = wih0[r*2 + 0];
    wx1[g] = wih0[r*2 + 1];
  }
  float cc0 = 0.f, cc1 = 0.f, cc2 = 0.f;

  // one K=256 matmul source accumulated into acc (split bf16: hi*hi + hi*lo + lo*hi)
  auto mm = [&](const unsigned short* __restrict__ sh, const unsigned short* __restrict__ sl,
                int mat, f32x4& acc){
    { // stage h tile (16 rows x 256) hi+lo
      int r = tid >> 4, cq = tid & 15;
      const unsigned short* gh = sh + (b0 + r)*256 + cq*16;
      const unsigned short* gl = sl + (b0 + r)*256 + cq*16;
      *(uint4*)&hs_hi[r][cq*16    ] = *(const uint4*)(gh    );
      *(uint4*)&hs_hi[r][cq*16 + 8] = *(const uint4*)(gh + 8);
      *(uint4*)&hs_lo[r][cq*16    ] = *(const uint4*)(gl    );
      *(uint4*)&hs_lo[r][cq*16 + 8] = *(const uint4*)(gl + 8);
    }
    __syncthreads();
    const unsigned short* wbh = wre_hi + mat*262144 + nt*16384;
    const unsigned short* wbl = wre_lo + mat*262144 + nt*16384;
    #pragma unroll
    for (int ch = 0; ch < 2; ++ch){
      { // stage W chunk: 64 rows x 128 k, hi+lo
        int r = tid >> 2, cq = tid & 3;
        #pragma unroll
        for (int j = 0; j < 4; ++j){
          int col = cq*32 + 8*j;
          *(uint4*)&wc_hi[r][col] = *(const uint4*)(wbh + r*256 + ch*128 + col);
          *(uint4*)&wc_lo[r][col] = *(const uint4*)(wbl + r*256 + ch*128 + col);
        }
      }
      __syncthreads();
      #pragma unroll
      for (int ks = 0; ks < 4; ++ks){
        int kf   = ch*128 + ks*32 + quad*8;   // col in hs
        int wcol =          ks*32 + quad*8;   // col in wc (chunk-local)
        bfrag8 a_hi = *(const bfrag8*)&hs_hi[m][kf];
        bfrag8 a_lo = *(const bfrag8*)&hs_lo[m][kf];
        bfrag8 b_hi = *(const bfrag8*)&wc_hi[wave*16 + m][wcol];
        bfrag8 b_lo = *(const bfrag8*)&wc_lo[wave*16 + m][wcol];
        acc = __builtin_amdgcn_mfma_f32_16x16x32_bf16(a_hi, b_hi, acc, 0, 0, 0);
        acc = __builtin_amdgcn_mfma_f32_16x16x32_bf16(a_hi, b_lo, acc, 0, 0, 0);
        acc = __builtin_amdgcn_mfma_f32_16x16x32_bf16(a_lo, b_hi, acc, 0, 0, 0);
      }
      __syncthreads();
    }
  };

  // writes wave's D tile to gates_s; D: row=(lane>>4)*4+reg (batch), col=lane&15 (n)
  auto spill_gates = [&](f32x4& acc){
    #pragma unroll
    for (int rg = 0; rg < 4; ++rg) gates_s[wave][quad*4 + rg][m] = acc[rg];
    __syncthreads();
  };

  auto update = [&](int l, float& c, float xi, float xf, float xg, float xo,
                    int p0) {
    float gi = gates_s[0][ub][un] + bsum[l][0] + xi;
    float gf = gates_s[1][ub][un] + bsum[l][1] + xf;
    float gg = gates_s[2][ub][un] + bsum[l][2] + xg;
    float go = gates_s[3][ub][un] + bsum[l][3] + xo;
    float iv = 1.f / (1.f + expf(-gi));
    float fv = 1.f / (1.f + expf(-gf));
    float gv = tanhf(gg);
    float ov = 1.f / (1.f + expf(-go));
    c = fv * c + iv * gv;
    float hv = ov * tanhf(c);
    int idx = ((p0*3 + l)*256 + (b0 + ub))*256 + (n0 + un);
    unsigned short hh = f2bf(hv);
    hb_hi[idx] = hh;
    hb_lo[idx] = f2bf(hv - bf2f(hh));
  };

  for (int t = 0; t < 512; ++t){
    const int p0 = t & 1, p1 = p0 ^ 1;

    // -------- layer 0: gates = hrec @ Whh0^T (+ x @ Wih0^T inline)
    f32x4 acc = {0.f, 0.f, 0.f, 0.f};
    mm(hb_hi + (p1*3 + 0)*65536, hb_lo + (p1*3 + 0)*65536, 0, acc);
    spill_gates(acc);
    {
      float x0 = tracks[(b0 + ub)*1024 + t*2 + 0];
      float x1 = tracks[(b0 + ub)*1024 + t*2 + 1];
      update(0, cc0, x0*wx0[0] + x1*wx1[0], x0*wx0[1] + x1*wx1[1],
                      x0*wx0[2] + x1*wx1[2], x0*wx0[3] + x1*wx1[3], p0);
    }
    grid.sync();

    // -------- layer 1: gates = h0[t] @ Wih1^T + h1[t-1] @ Whh1^T
    acc = (f32x4){0.f, 0.f, 0.f, 0.f};
    mm(hb_hi + (p0*3 + 0)*65536, hb_lo + (p0*3 + 0)*65536, 1, acc);
    mm(hb_hi + (p1*3 + 1)*65536, hb_lo + (p1*3 + 1)*65536, 2, acc);
    spill_gates(acc);
    update(1, cc1, 0.f, 0.f, 0.f, 0.f, p0);
    grid.sync();

    // -------- layer 2: gates = h1[t] @ Wih2^T + h2[t-1] @ Whh2^T
    acc = (f32x4){0.f, 0.f, 0.f, 0.f};
    mm(hb_hi + (p0*3 + 1)*65536, hb_lo + (p0*3 + 1)*65536, 3, acc);
    mm(hb_hi + (p1*3 + 2)*65536, hb_lo + (p1*3 + 2)*65536, 4, acc);
    spill_gates(acc);
    update(2, cc2, 0.f, 0.f, 0.f, 0.f, p0);
    // no grid.sync needed: h2[t] first re-read at (t+1,l2), >= 2 syncs away;
    // all t+1 layer-0 deps protected by the two syncs above.
  }
}

// out[b] = elu(h2_final[b]) @ W_pred^T + b_pred ; h2 final parity = 511&1 = 1 -> plane 5
__global__ void head_kernel(const unsigned short* __restrict__ hb_hi,
                            const unsigned short* __restrict__ hb_lo,
                            const float* __restrict__ wpred,
                            const float* __restrict__ bpred,
                            float* __restrict__ out){
  const int b = blockIdx.x;
  const int k = threadIdx.x;
  const int idx = 5*65536 + b*256 + k;
  float h = bf2f(hb_hi[idx]) + bf2f(hb_lo[idx]);
  float e = (h > 0.f) ? h : expm1f(h);
  float v0 = e * wpred[k];
  float v1 = e * wpred[256 + k];
  #pragma unroll
  for (int off = 32; off > 0; off >>= 1){
    v0 += __shfl_down(v0, off, 64);
    v1 += __shfl_down(v1, off, 64);
  }
  __shared__ float r0[4], r1[4];
  int wv = threadIdx.x >> 6, ln = threadIdx.x & 63;
  if (ln == 0){ r0[wv] = v0; r1[wv] = v1; }
  __syncthreads();
  if (threadIdx.x == 0){
    out[b*2 + 0] = r0[0] + r0[1] + r0[2] + r0[3] + bpred[0];
    out[b*2 + 1] = r1[0] + r1[1] + r1[2] + r1[3] + bpred[1];
  }
}

extern "C" void kernel_launch(void* const* d_in, const int* in_sizes, int n_in,
                              void* d_out, int out_size, void* d_ws, size_t ws_size,
                              hipStream_t stream) {
  const float* tracks = (const float*)d_in[0];
  const float* wih0   = (const float*)d_in[1];
  const float* whh0   = (const float*)d_in[2];
  const float* bih0   = (const float*)d_in[3];
  const float* bhh0   = (const float*)d_in[4];
  const float* wih1   = (const float*)d_in[5];
  const float* whh1   = (const float*)d_in[6];
  const float* bih1   = (const float*)d_in[7];
  const float* bhh1   = (const float*)d_in[8];
  const float* wih2   = (const float*)d_in[9];
  const float* whh2   = (const float*)d_in[10];
  const float* bih2   = (const float*)d_in[11];
  const float* bhh2   = (const float*)d_in[12];
  const float* wpred  = (const float*)d_in[13];
  const float* bpred  = (const float*)d_in[14];
  float* out = (float*)d_out;

  char* ws = (char*)d_ws;
  unsigned short* wre_hi = (unsigned short*)(ws);
  unsigned short* wre_lo = (unsigned short*)(ws + WRE_LO_OFF);
  unsigned short* hb_hi  = (unsigned short*)(ws + HB_HI_OFF);
  unsigned short* hb_lo  = (unsigned short*)(ws + HB_LO_OFF);

  init_reorder<<<5120, 256, 0, stream>>>(whh0, wih1, whh1, wih2, whh2, wre_hi, wre_lo);
  init_zero<<<384, 256, 0, stream>>>((uint4*)(ws + HB_HI_OFF));

  void* args[12];
  args[0]  = (void*)&tracks;
  args[1]  = (void*)&wih0;
  args[2]  = (void*)&bih0;
  args[3]  = (void*)&bhh0;
  args[4]  = (void*)&bih1;
  args[5]  = (void*)&bhh1;
  args[6]  = (void*)&bih2;
  args[7]  = (void*)&bhh2;
  args[8]  = (void*)&wre_hi;
  args[9]  = (void*)&wre_lo;
  args[10] = (void*)&hb_hi;
  args[11] = (void*)&hb_lo;
  hipLaunchCooperativeKernel((const void*)lstm_coop, dim3(256), dim3(256), args, 0, stream);

  head_kernel<<<256, 256, 0, stream>>>(hb_hi, hb_lo, wpred, bpred, out);
}

// Round 3
// 13393.121 us; speedup vs baseline: 3.7334x; 3.7334x over previous
//
#include <hip/hip_runtime.h>
#include <hip/hip_cooperative_groups.h>
#include <math.h>

namespace cg = cooperative_groups;

typedef __attribute__((ext_vector_type(4))) float f32x4;
typedef __attribute__((ext_vector_type(8))) short bfrag8;   // 8 bf16 = 4 VGPRs

// ---- ws layout (bytes) ----
// wre_hi: 5 mats * 1024 * 256 * 2B = 2621440 @ 0
// wre_lo: same                              @ 2621440
// hb    : 2 par * 3 layers * 256*256 * 2B = 786432 @ 5242880
#define WRE_LO_OFF 2621440
#define HB_OFF     5242880

// dynamic LDS: [2 mats][2 planes][64 rows][264 bf16]  = 4*64*264*2 = 135168 B
#define WROW 264
#define SMEM_BYTES (4 * 64 * WROW * 2)

__device__ __forceinline__ unsigned short f2bf(float f){
  union { float f; unsigned u; } x; x.f = f;
  unsigned r = x.u + 0x7FFFu + ((x.u >> 16) & 1u);   // RNE
  return (unsigned short)(r >> 16);
}
__device__ __forceinline__ float bf2f(unsigned short s){
  union { unsigned u; float f; } x; x.u = ((unsigned)s) << 16; return x.f;
}
__device__ __forceinline__ float sigf(float x){
  return 1.0f / (1.0f + __expf(-x));
}
__device__ __forceinline__ float tanh_fast(float x){
  x = fminf(fmaxf(x, -15.0f), 15.0f);
  float e = __expf(2.0f * x);
  return (e - 1.0f) / (e + 1.0f);
}

// Reorder the 5 big weight mats into per-(nt)-contiguous rows, split bf16 hi/lo.
// dest row d in [0,1024): nt=d>>6, g=(d>>4)&3, n=d&15 ; src row = g*256 + nt*16 + n
// => within an nt-slice, row r = g*16+n, contiguous 64 rows of 256.
__global__ void init_reorder(const float* __restrict__ hh0, const float* __restrict__ ih1,
                             const float* __restrict__ hh1, const float* __restrict__ ih2,
                             const float* __restrict__ hh2,
                             unsigned short* __restrict__ wre_hi,
                             unsigned short* __restrict__ wre_lo){
  int e = blockIdx.x * 256 + threadIdx.x;        // 5*2^18 total
  int mat = e >> 18;
  int d   = (e >> 8) & 1023;
  int k   = e & 255;
  int nt = d >> 6, g = (d >> 4) & 3, n = d & 15;
  int src_row = g*256 + nt*16 + n;
  const float* W = (mat==0) ? hh0 : (mat==1) ? ih1 : (mat==2) ? hh1 : (mat==3) ? ih2 : hh2;
  float v = W[src_row*256 + k];
  unsigned short hi = f2bf(v);
  float lo = v - bf2f(hi);
  wre_hi[e] = hi;
  wre_lo[e] = f2bf(lo);
}

__global__ void init_zero(uint4* __restrict__ p){
  int i = blockIdx.x * 256 + threadIdx.x;        // 192*256 = 49152 * 16B = 786432 B
  p[i] = make_uint4(0u,0u,0u,0u);
}

// Layer-pipelined LSTM. 192 blocks = layer(3) x nt(16) x bt(4).
// Block (l, nt, bt): 64 batch rows [bt*64, +64), 64 gate rows (4 gates x 16 n at nt*16).
// Weights persist in LDS (hi/lo). One grid.sync per global step.
__global__ void lstm_coop(
    const float* __restrict__ tracks,
    const float* __restrict__ wih0,
    const float* __restrict__ bih0, const float* __restrict__ bhh0,
    const float* __restrict__ bih1, const float* __restrict__ bhh1,
    const float* __restrict__ bih2, const float* __restrict__ bhh2,
    const unsigned short* __restrict__ wre_hi, const unsigned short* __restrict__ wre_lo,
    unsigned short* __restrict__ hb)
{
  cg::grid_group grid = cg::this_grid();
  extern __shared__ __align__(16) unsigned short smem[];   // [mat][plane][64][WROW]

  const int tid  = threadIdx.x;
  const int l    = blockIdx.x >> 6;
  const int r6   = blockIdx.x & 63;
  const int nt   = r6 & 15, bt = r6 >> 4;
  const int b0   = bt * 64, n0 = nt * 16;
  const int w    = tid >> 6, lane = tid & 63;
  const int m    = lane & 15, q = lane >> 4;

  // ---- stage this layer's weight slices into LDS (once) ----
  // each slice: 64 rows x 256 shorts -> 2048 uint4-loads of 8 shorts
  const int nmats = (l == 0) ? 1 : 2;
  const int gmat0 = (l == 0) ? 0 : (l == 1 ? 1 : 3);
  for (int mi = 0; mi < nmats; ++mi){
    const unsigned short* sh = wre_hi + (gmat0 + mi)*262144 + nt*16384;
    const unsigned short* sl = wre_lo + (gmat0 + mi)*262144 + nt*16384;
    unsigned short* dh = smem + (mi*2 + 0)*64*WROW;
    unsigned short* dl = smem + (mi*2 + 1)*64*WROW;
    for (int c = tid; c < 2048; c += 256){
      int r = c >> 5, off = (c & 31) * 8;     // FIX: full 256-col rows (was 128)
      *(uint4*)(dh + r*WROW + off) = *(const uint4*)(sh + r*256 + off);
      *(uint4*)(dl + r*WROW + off) = *(const uint4*)(sl + r*256 + off);
    }
  }
  __syncthreads();

  // ---- per-lane persistent state ----
  // lane owns 4 cells: batch rows b0 + 16w + q*4 + r (r=0..3), hidden col n0 + m
  const float* bihL = (l==0) ? bih0 : (l==1) ? bih1 : bih2;
  const float* bhhL = (l==0) ? bhh0 : (l==1) ? bhh1 : bhh2;
  float bsum[4], wx[4][2];
  #pragma unroll
  for (int g = 0; g < 4; ++g){
    int row = g*256 + n0 + m;
    bsum[g] = bihL[row] + bhhL[row];
    wx[g][0] = wih0[row*2 + 0];
    wx[g][1] = wih0[row*2 + 1];
  }
  float cst[4] = {0.f, 0.f, 0.f, 0.f};
  const int arow = b0 + 16*w + m;                  // A-fragment batch row for this lane
  const int woff = m*WROW + q*8;                   // per-lane B-frag LDS offset (shorts)
  // mat slot layout: slot0 = (l==0? Whh0 : Wih_l), slot1 = Whh_l (l>=1)

  for (int s = 0; s < 514; ++s){
    const int t = s - l;
    const bool active = (t >= 0) && (t < 512);

    if (active){
      const int pt = t & 1, pp = pt ^ 1;

      // ---- prefetch A fragments from global (L2-resident h buffers) ----
      bfrag8 a_in[8], a_rec[8];
      {
        const unsigned short* prec = hb + ((pp*3 + l)*256 + arow)*256;
        #pragma unroll
        for (int ks = 0; ks < 8; ++ks)
          a_rec[ks] = *(const bfrag8*)(prec + ks*32 + q*8);
        if (l >= 1){
          const unsigned short* pin = hb + ((pt*3 + (l-1))*256 + arow)*256;
          #pragma unroll
          for (int ks = 0; ks < 8; ++ks)
            a_in[ks] = *(const bfrag8*)(pin + ks*32 + q*8);
        }
      }
      // layer-0 input term: x_t (2-dim) per owned batch row
      float xv0[4], xv1[4];
      if (l == 0){
        #pragma unroll
        for (int r = 0; r < 4; ++r){
          const float* px = tracks + (b0 + 16*w + q*4 + r)*1024 + t*2;
          xv0[r] = px[0]; xv1[r] = px[1];
        }
      }

      // ---- MFMA: acc[g] over K=256, W split hi/lo ----
      f32x4 acc[4];
      #pragma unroll
      for (int g = 0; g < 4; ++g) acc[g] = (f32x4){0.f,0.f,0.f,0.f};

      // recurrent mat: slot (l==0 ? 0 : 1)
      {
        const unsigned short* bh = smem + ((l==0?0:2) + 0)*64*WROW + woff;
        const unsigned short* bl = smem + ((l==0?0:2) + 1)*64*WROW + woff;
        #pragma unroll
        for (int ks = 0; ks < 8; ++ks){
          #pragma unroll
          for (int g = 0; g < 4; ++g){
            bfrag8 fh = *(const bfrag8*)(bh + g*16*WROW + ks*32);
            bfrag8 fl = *(const bfrag8*)(bl + g*16*WROW + ks*32);
            acc[g] = __builtin_amdgcn_mfma_f32_16x16x32_bf16(a_rec[ks], fh, acc[g], 0, 0, 0);
            acc[g] = __builtin_amdgcn_mfma_f32_16x16x32_bf16(a_rec[ks], fl, acc[g], 0, 0, 0);
          }
        }
      }
      // input mat (layers 1,2): slot 0
      if (l >= 1){
        const unsigned short* bh = smem + 0*64*WROW + woff;
        const unsigned short* bl = smem + 1*64*WROW + woff;
        #pragma unroll
        for (int ks = 0; ks < 8; ++ks){
          #pragma unroll
          for (int g = 0; g < 4; ++g){
            bfrag8 fh = *(const bfrag8*)(bh + g*16*WROW + ks*32);
            bfrag8 fl = *(const bfrag8*)(bl + g*16*WROW + ks*32);
            acc[g] = __builtin_amdgcn_mfma_f32_16x16x32_bf16(a_in[ks], fh, acc[g], 0, 0, 0);
            acc[g] = __builtin_amdgcn_mfma_f32_16x16x32_bf16(a_in[ks], fl, acc[g], 0, 0, 0);
          }
        }
      }

      // ---- cell update (gates live in this lane's registers; c exact fp32) ----
      unsigned short* hout = hb + ((pt*3 + l)*256 + 0)*256;
      #pragma unroll
      for (int r = 0; r < 4; ++r){
        float xi = 0.f, xf = 0.f, xg = 0.f, xo = 0.f;
        if (l == 0){
          xi = xv0[r]*wx[0][0] + xv1[r]*wx[0][1];
          xf = xv0[r]*wx[1][0] + xv1[r]*wx[1][1];
          xg = xv0[r]*wx[2][0] + xv1[r]*wx[2][1];
          xo = xv0[r]*wx[3][0] + xv1[r]*wx[3][1];
        }
        float gi = acc[0][r] + bsum[0] + xi;
        float gf = acc[1][r] + bsum[1] + xf;
        float gg = acc[2][r] + bsum[2] + xg;
        float go = acc[3][r] + bsum[3] + xo;
        float iv = sigf(gi);
        float fv = sigf(gf);
        float gv = tanh_fast(gg);
        float ov = sigf(go);
        cst[r] = fv * cst[r] + iv * gv;
        float hv = ov * tanh_fast(cst[r]);
        hout[(b0 + 16*w + q*4 + r)*256 + n0 + m] = f2bf(hv);
      }
    }

    grid.sync();
  }
}

// out[b] = elu(h2_final[b]) @ W_pred^T + b_pred ; h2 final parity = 511&1 = 1 -> plane (1,2)=5
__global__ void head_kernel(const unsigned short* __restrict__ hb,
                            const float* __restrict__ wpred,
                            const float* __restrict__ bpred,
                            float* __restrict__ out){
  const int b = blockIdx.x;
  const int k = threadIdx.x;
  const int idx = (5*256 + b)*256 + k;
  float h = bf2f(hb[idx]);
  float e = (h > 0.f) ? h : expm1f(h);
  float v0 = e * wpred[k];
  float v1 = e * wpred[256 + k];
  #pragma unroll
  for (int off = 32; off > 0; off >>= 1){
    v0 += __shfl_down(v0, off, 64);
    v1 += __shfl_down(v1, off, 64);
  }
  __shared__ float r0[4], r1[4];
  int wv = threadIdx.x >> 6, ln = threadIdx.x & 63;
  if (ln == 0){ r0[wv] = v0; r1[wv] = v1; }
  __syncthreads();
  if (threadIdx.x == 0){
    out[b*2 + 0] = r0[0] + r0[1] + r0[2] + r0[3] + bpred[0];
    out[b*2 + 1] = r1[0] + r1[1] + r1[2] + r1[3] + bpred[1];
  }
}

extern "C" void kernel_launch(void* const* d_in, const int* in_sizes, int n_in,
                              void* d_out, int out_size, void* d_ws, size_t ws_size,
                              hipStream_t stream) {
  const float* tracks = (const float*)d_in[0];
  const float* wih0   = (const float*)d_in[1];
  const float* whh0   = (const float*)d_in[2];
  const float* bih0   = (const float*)d_in[3];
  const float* bhh0   = (const float*)d_in[4];
  const float* wih1   = (const float*)d_in[5];
  const float* whh1   = (const float*)d_in[6];
  const float* bih1   = (const float*)d_in[7];
  const float* bhh1   = (const float*)d_in[8];
  const float* wih2   = (const float*)d_in[9];
  const float* whh2   = (const float*)d_in[10];
  const float* bih2   = (const float*)d_in[11];
  const float* bhh2   = (const float*)d_in[12];
  const float* wpred  = (const float*)d_in[13];
  const float* bpred  = (const float*)d_in[14];
  float* out = (float*)d_out;

  char* ws = (char*)d_ws;
  unsigned short* wre_hi = (unsigned short*)(ws);
  unsigned short* wre_lo = (unsigned short*)(ws + WRE_LO_OFF);
  unsigned short* hb     = (unsigned short*)(ws + HB_OFF);

  // allow 132 KB dynamic LDS (gfx950: 160 KB/CU)
  (void)hipFuncSetAttribute((const void*)lstm_coop,
                            hipFuncAttributeMaxDynamicSharedMemorySize, SMEM_BYTES);

  init_reorder<<<5120, 256, 0, stream>>>(whh0, wih1, whh1, wih2, whh2, wre_hi, wre_lo);
  init_zero<<<192, 256, 0, stream>>>((uint4*)(ws + HB_OFF));

  void* args[11];
  args[0]  = (void*)&tracks;
  args[1]  = (void*)&wih0;
  args[2]  = (void*)&bih0;
  args[3]  = (void*)&bhh0;
  args[4]  = (void*)&bih1;
  args[5]  = (void*)&bhh1;
  args[6]  = (void*)&bih2;
  args[7]  = (void*)&bhh2;
  args[8]  = (void*)&wre_hi;
  args[9]  = (void*)&wre_lo;
  args[10] = (void*)&hb;
  hipLaunchCooperativeKernel((const void*)lstm_coop, dim3(192), dim3(256), args,
                             SMEM_BYTES, stream);

  head_kernel<<<256, 256, 0, stream>>>(hb, wpred, bpred, out);
}

// Round 4
// 5982.679 us; speedup vs baseline: 8.3578x; 2.2386x over previous
//
#include <hip/hip_runtime.h>
#include <math.h>

typedef __attribute__((ext_vector_type(4))) float f32x4;
typedef __attribute__((ext_vector_type(8))) short bfrag8;   // 8 bf16 = 4 VGPRs

// ---- ws layout (bytes) ----
// wre_hi: 5 mats * 1024 * 256 * 2B = 2621440 @ 0
// wre_lo: same                              @ 2621440
// hb    : 2 par * 3 layers * 256*256 * 2B = 786432 @ 5242880
// flags : 4 columns * 64 ints              @ 6029312  (1024 B)
#define WRE_LO_OFF 2621440
#define HB_OFF     5242880
#define FLAGS_OFF  6029312

// dynamic LDS: [2 mats][2 planes][64 rows][264 bf16]  = 4*64*264*2 = 135168 B
#define WROW 264
#define SMEM_BYTES (4 * 64 * WROW * 2)

__device__ __forceinline__ unsigned short f2bf(float f){
  union { float f; unsigned u; } x; x.f = f;
  unsigned r = x.u + 0x7FFFu + ((x.u >> 16) & 1u);   // RNE
  return (unsigned short)(r >> 16);
}
__device__ __forceinline__ float bf2f(unsigned short s){
  union { unsigned u; float f; } x; x.u = ((unsigned)s) << 16; return x.f;
}
__device__ __forceinline__ float sigf(float x){
  return 1.0f / (1.0f + __expf(-x));
}
__device__ __forceinline__ float tanh_fast(float x){
  x = fminf(fmaxf(x, -15.0f), 15.0f);
  float e = __expf(2.0f * x);
  return (e - 1.0f) / (e + 1.0f);
}

// Reorder the 5 big weight mats into per-(nt)-contiguous rows, split bf16 hi/lo.
// dest row d in [0,1024): nt=d>>6, g=(d>>4)&3, n=d&15 ; src row = g*256 + nt*16 + n
__global__ void init_reorder(const float* __restrict__ hh0, const float* __restrict__ ih1,
                             const float* __restrict__ hh1, const float* __restrict__ ih2,
                             const float* __restrict__ hh2,
                             unsigned short* __restrict__ wre_hi,
                             unsigned short* __restrict__ wre_lo){
  int e = blockIdx.x * 256 + threadIdx.x;        // 5*2^18 total
  int mat = e >> 18;
  int d   = (e >> 8) & 1023;
  int k   = e & 255;
  int nt = d >> 6, g = (d >> 4) & 3, n = d & 15;
  int src_row = g*256 + nt*16 + n;
  const float* W = (mat==0) ? hh0 : (mat==1) ? ih1 : (mat==2) ? hh1 : (mat==3) ? ih2 : hh2;
  float v = W[src_row*256 + k];
  unsigned short hi = f2bf(v);
  float lo = v - bf2f(hi);
  wre_hi[e] = hi;
  wre_lo[e] = f2bf(lo);
}

__global__ void init_zero(uint4* __restrict__ p, int n16){
  int i = blockIdx.x * 256 + threadIdx.x;
  if (i < n16) p[i] = make_uint4(0u,0u,0u,0u);
}

// Layer-pipelined LSTM. 192 blocks = layer(3) x nt(16) x bt(4).
// Block (l, nt, bt): 64 batch rows [bt*64, +64), 64 gate rows (4 gates x 16 n at nt*16).
// Weights persist in LDS (hi/lo). Per-bt-column monotone barrier (48 blocks):
// after step s each block adds 1 to its column counter (release/agent);
// before step s it spins until counter >= 48*s (acquire/agent).
// Monotone-sum barrier => max skew 1 step => parity double-buffer RAW/WAR safe.
__global__ void lstm_coop(
    const float* __restrict__ tracks,
    const float* __restrict__ wih0,
    const float* __restrict__ bih0, const float* __restrict__ bhh0,
    const float* __restrict__ bih1, const float* __restrict__ bhh1,
    const float* __restrict__ bih2, const float* __restrict__ bhh2,
    const unsigned short* __restrict__ wre_hi, const unsigned short* __restrict__ wre_lo,
    unsigned short* __restrict__ hb, unsigned int* __restrict__ flags)
{
  extern __shared__ __align__(16) unsigned short smem[];   // [mat][plane][64][WROW]

  const int tid  = threadIdx.x;
  const int l    = blockIdx.x >> 6;
  const int r6   = blockIdx.x & 63;
  const int nt   = r6 & 15, bt = r6 >> 4;
  const int b0   = bt * 64, n0 = nt * 16;
  const int w    = tid >> 6, lane = tid & 63;
  const int m    = lane & 15, q = lane >> 4;

  unsigned int* cnt = flags + bt * 64;   // own 256B line per column

  // ---- stage this layer's weight slices into LDS (once) ----
  const int nmats = (l == 0) ? 1 : 2;
  const int gmat0 = (l == 0) ? 0 : (l == 1 ? 1 : 3);
  for (int mi = 0; mi < nmats; ++mi){
    const unsigned short* sh = wre_hi + (gmat0 + mi)*262144 + nt*16384;
    const unsigned short* sl = wre_lo + (gmat0 + mi)*262144 + nt*16384;
    unsigned short* dh = smem + (mi*2 + 0)*64*WROW;
    unsigned short* dl = smem + (mi*2 + 1)*64*WROW;
    for (int c = tid; c < 2048; c += 256){
      int r = c >> 5, off = (c & 31) * 8;
      *(uint4*)(dh + r*WROW + off) = *(const uint4*)(sh + r*256 + off);
      *(uint4*)(dl + r*WROW + off) = *(const uint4*)(sl + r*256 + off);
    }
  }
  __syncthreads();

  // ---- per-lane persistent state ----
  const float* bihL = (l==0) ? bih0 : (l==1) ? bih1 : bih2;
  const float* bhhL = (l==0) ? bhh0 : (l==1) ? bhh1 : bhh2;
  float bsum[4], wx[4][2];
  #pragma unroll
  for (int g = 0; g < 4; ++g){
    int row = g*256 + n0 + m;
    bsum[g] = bihL[row] + bhhL[row];
    wx[g][0] = wih0[row*2 + 0];
    wx[g][1] = wih0[row*2 + 1];
  }
  float cst[4] = {0.f, 0.f, 0.f, 0.f};
  const int arow = b0 + 16*w + m;                  // A-fragment batch row for this lane
  const int woff = m*WROW + q*8;                   // per-lane B-frag LDS offset (shorts)

  for (int s = 0; s < 514; ++s){
    // ---- column barrier wait: all 48 column blocks finished step s-1 ----
    if (s > 0){
      if (tid == 0){
        const unsigned int tgt = 48u * (unsigned)s;
        while (__hip_atomic_load(cnt, __ATOMIC_RELAXED, __HIP_MEMORY_SCOPE_AGENT) < tgt)
          __builtin_amdgcn_s_sleep(2);
        (void)__hip_atomic_load(cnt, __ATOMIC_ACQUIRE, __HIP_MEMORY_SCOPE_AGENT);
      }
      __syncthreads();
    }

    const int t = s - l;
    const bool active = (t >= 0) && (t < 512);

    if (active){
      const int pt = t & 1, pp = pt ^ 1;

      // ---- A fragments from global (LLC-resident h buffers) ----
      bfrag8 a_in[8], a_rec[8];
      {
        const unsigned short* prec = hb + ((pp*3 + l)*256 + arow)*256;
        #pragma unroll
        for (int ks = 0; ks < 8; ++ks)
          a_rec[ks] = *(const bfrag8*)(prec + ks*32 + q*8);
        if (l >= 1){
          const unsigned short* pin = hb + ((pt*3 + (l-1))*256 + arow)*256;
          #pragma unroll
          for (int ks = 0; ks < 8; ++ks)
            a_in[ks] = *(const bfrag8*)(pin + ks*32 + q*8);
        }
      }
      float xv0[4], xv1[4];
      if (l == 0){
        #pragma unroll
        for (int r = 0; r < 4; ++r){
          const float* px = tracks + (b0 + 16*w + q*4 + r)*1024 + t*2;
          xv0[r] = px[0]; xv1[r] = px[1];
        }
      }

      // ---- MFMA: acc[g] over K=256, W split hi/lo ----
      f32x4 acc[4];
      #pragma unroll
      for (int g = 0; g < 4; ++g) acc[g] = (f32x4){0.f,0.f,0.f,0.f};

      { // recurrent mat: slot (l==0 ? 0 : 1)
        const unsigned short* bh = smem + ((l==0?0:2) + 0)*64*WROW + woff;
        const unsigned short* bl = smem + ((l==0?0:2) + 1)*64*WROW + woff;
        #pragma unroll
        for (int ks = 0; ks < 8; ++ks){
          #pragma unroll
          for (int g = 0; g < 4; ++g){
            bfrag8 fh = *(const bfrag8*)(bh + g*16*WROW + ks*32);
            bfrag8 fl = *(const bfrag8*)(bl + g*16*WROW + ks*32);
            acc[g] = __builtin_amdgcn_mfma_f32_16x16x32_bf16(a_rec[ks], fh, acc[g], 0, 0, 0);
            acc[g] = __builtin_amdgcn_mfma_f32_16x16x32_bf16(a_rec[ks], fl, acc[g], 0, 0, 0);
          }
        }
      }
      if (l >= 1){ // input mat: slot 0
        const unsigned short* bh = smem + 0*64*WROW + woff;
        const unsigned short* bl = smem + 1*64*WROW + woff;
        #pragma unroll
        for (int ks = 0; ks < 8; ++ks){
          #pragma unroll
          for (int g = 0; g < 4; ++g){
            bfrag8 fh = *(const bfrag8*)(bh + g*16*WROW + ks*32);
            bfrag8 fl = *(const bfrag8*)(bl + g*16*WROW + ks*32);
            acc[g] = __builtin_amdgcn_mfma_f32_16x16x32_bf16(a_in[ks], fh, acc[g], 0, 0, 0);
            acc[g] = __builtin_amdgcn_mfma_f32_16x16x32_bf16(a_in[ks], fl, acc[g], 0, 0, 0);
          }
        }
      }

      // ---- cell update (gates in registers; c exact fp32) ----
      unsigned short* hout = hb + ((pt*3 + l)*256 + 0)*256;
      #pragma unroll
      for (int r = 0; r < 4; ++r){
        float xi = 0.f, xf = 0.f, xg = 0.f, xo = 0.f;
        if (l == 0){
          xi = xv0[r]*wx[0][0] + xv1[r]*wx[0][1];
          xf = xv0[r]*wx[1][0] + xv1[r]*wx[1][1];
          xg = xv0[r]*wx[2][0] + xv1[r]*wx[2][1];
          xo = xv0[r]*wx[3][0] + xv1[r]*wx[3][1];
        }
        float gi = acc[0][r] + bsum[0] + xi;
        float gf = acc[1][r] + bsum[1] + xf;
        float gg = acc[2][r] + bsum[2] + xg;
        float go = acc[3][r] + bsum[3] + xo;
        float iv = sigf(gi);
        float fv = sigf(gf);
        float gv = tanh_fast(gg);
        float ov = sigf(go);
        cst[r] = fv * cst[r] + iv * gv;
        float hv = ov * tanh_fast(cst[r]);
        hout[(b0 + 16*w + q*4 + r)*256 + n0 + m] = f2bf(hv);
      }
    }

    // ---- column barrier arrive: stores drained (syncthreads waits vmcnt(0)
    // per wave), then one release-add (emits L2 writeback for cross-XCD) ----
    __syncthreads();
    if (tid == 0)
      __hip_atomic_fetch_add(cnt, 1u, __ATOMIC_RELEASE, __HIP_MEMORY_SCOPE_AGENT);
  }
}

// out[b] = elu(h2_final[b]) @ W_pred^T + b_pred ; h2 final parity = 511&1 = 1 -> plane 5
__global__ void head_kernel(const unsigned short* __restrict__ hb,
                            const float* __restrict__ wpred,
                            const float* __restrict__ bpred,
                            float* __restrict__ out){
  const int b = blockIdx.x;
  const int k = threadIdx.x;
  const int idx = (5*256 + b)*256 + k;
  float h = bf2f(hb[idx]);
  float e = (h > 0.f) ? h : expm1f(h);
  float v0 = e * wpred[k];
  float v1 = e * wpred[256 + k];
  #pragma unroll
  for (int off = 32; off > 0; off >>= 1){
    v0 += __shfl_down(v0, off, 64);
    v1 += __shfl_down(v1, off, 64);
  }
  __shared__ float r0[4], r1[4];
  int wv = threadIdx.x >> 6, ln = threadIdx.x & 63;
  if (ln == 0){ r0[wv] = v0; r1[wv] = v1; }
  __syncthreads();
  if (threadIdx.x == 0){
    out[b*2 + 0] = r0[0] + r0[1] + r0[2] + r0[3] + bpred[0];
    out[b*2 + 1] = r1[0] + r1[1] + r1[2] + r1[3] + bpred[1];
  }
}

extern "C" void kernel_launch(void* const* d_in, const int* in_sizes, int n_in,
                              void* d_out, int out_size, void* d_ws, size_t ws_size,
                              hipStream_t stream) {
  const float* tracks = (const float*)d_in[0];
  const float* wih0   = (const float*)d_in[1];
  const float* whh0   = (const float*)d_in[2];
  const float* bih0   = (const float*)d_in[3];
  const float* bhh0   = (const float*)d_in[4];
  const float* wih1   = (const float*)d_in[5];
  const float* whh1   = (const float*)d_in[6];
  const float* bih1   = (const float*)d_in[7];
  const float* bhh1   = (const float*)d_in[8];
  const float* wih2   = (const float*)d_in[9];
  const float* whh2   = (const float*)d_in[10];
  const float* bih2   = (const float*)d_in[11];
  const float* bhh2   = (const float*)d_in[12];
  const float* wpred  = (const float*)d_in[13];
  const float* bpred  = (const float*)d_in[14];
  float* out = (float*)d_out;

  char* ws = (char*)d_ws;
  unsigned short* wre_hi = (unsigned short*)(ws);
  unsigned short* wre_lo = (unsigned short*)(ws + WRE_LO_OFF);
  unsigned short* hb     = (unsigned short*)(ws + HB_OFF);
  unsigned int*   flags  = (unsigned int*)(ws + FLAGS_OFF);

  (void)hipFuncSetAttribute((const void*)lstm_coop,
                            hipFuncAttributeMaxDynamicSharedMemorySize, SMEM_BYTES);

  init_reorder<<<5120, 256, 0, stream>>>(whh0, wih1, whh1, wih2, whh2, wre_hi, wre_lo);
  // zero hb (786432 B) + flags (1024 B) = 787456 B = 49216 uint4
  init_zero<<<193, 256, 0, stream>>>((uint4*)(ws + HB_OFF), 49216);

  void* args[12];
  args[0]  = (void*)&tracks;
  args[1]  = (void*)&wih0;
  args[2]  = (void*)&bih0;
  args[3]  = (void*)&bhh0;
  args[4]  = (void*)&bih1;
  args[5]  = (void*)&bhh1;
  args[6]  = (void*)&bih2;
  args[7]  = (void*)&bhh2;
  args[8]  = (void*)&wre_hi;
  args[9]  = (void*)&wre_lo;
  args[10] = (void*)&hb;
  args[11] = (void*)&flags;
  // cooperative launch kept purely for the all-blocks-co-resident guarantee
  hipLaunchCooperativeKernel((const void*)lstm_coop, dim3(192), dim3(256), args,
                             SMEM_BYTES, stream);

  head_kernel<<<256, 256, 0, stream>>>(hb, wpred, bpred, out);
}

// Round 5
// 5683.517 us; speedup vs baseline: 8.7977x; 1.0526x over previous
//
#include <hip/hip_runtime.h>
#include <math.h>

typedef __attribute__((ext_vector_type(4))) float f32x4;
typedef __attribute__((ext_vector_type(8))) short bfrag8;   // 8 bf16 = 4 VGPRs

// ---- ws layout (bytes) ----
// wre_hi: 5 mats * 1024 * 256 * 2B = 2621440 @ 0
// wre_lo: same                              @ 2621440
// hb    : 2 par * 3 layers * 256*256 * 2B = 786432 @ 5242880
// flags : 4 columns * 16 subcounters * 64 uints = 16384 B @ 6029312
#define WRE_LO_OFF 2621440
#define HB_OFF     5242880
#define FLAGS_OFF  6029312

// dynamic LDS: [2 mats][2 planes][64 rows][264 bf16]  = 4*64*264*2 = 135168 B
#define WROW 264
#define SMEM_BYTES (4 * 64 * WROW * 2)

__device__ __forceinline__ unsigned short f2bf(float f){
  union { float f; unsigned u; } x; x.f = f;
  unsigned r = x.u + 0x7FFFu + ((x.u >> 16) & 1u);   // RNE
  return (unsigned short)(r >> 16);
}
__device__ __forceinline__ float bf2f(unsigned short s){
  union { unsigned u; float f; } x; x.u = ((unsigned)s) << 16; return x.f;
}
__device__ __forceinline__ float sigf(float x){
  return 1.0f / (1.0f + __expf(-x));
}
__device__ __forceinline__ float tanh_fast(float x){
  x = fminf(fmaxf(x, -15.0f), 15.0f);
  float e = __expf(2.0f * x);
  return (e - 1.0f) / (e + 1.0f);
}

// Reorder the 5 big weight mats into per-(nt)-contiguous rows, split bf16 hi/lo.
// dest row d in [0,1024): nt=d>>6, g=(d>>4)&3, n=d&15 ; src row = g*256 + nt*16 + n
__global__ void init_reorder(const float* __restrict__ hh0, const float* __restrict__ ih1,
                             const float* __restrict__ hh1, const float* __restrict__ ih2,
                             const float* __restrict__ hh2,
                             unsigned short* __restrict__ wre_hi,
                             unsigned short* __restrict__ wre_lo){
  int e = blockIdx.x * 256 + threadIdx.x;        // 5*2^18 total
  int mat = e >> 18;
  int d   = (e >> 8) & 1023;
  int k   = e & 255;
  int nt = d >> 6, g = (d >> 4) & 3, n = d & 15;
  int src_row = g*256 + nt*16 + n;
  const float* W = (mat==0) ? hh0 : (mat==1) ? ih1 : (mat==2) ? hh1 : (mat==3) ? ih2 : hh2;
  float v = W[src_row*256 + k];
  unsigned short hi = f2bf(v);
  float lo = v - bf2f(hi);
  wre_hi[e] = hi;
  wre_lo[e] = f2bf(lo);
}

__global__ void init_zero(uint4* __restrict__ p, int n16){
  int i = blockIdx.x * 256 + threadIdx.x;
  if (i < n16) p[i] = make_uint4(0u,0u,0u,0u);
}

// Layer-pipelined LSTM. 192 blocks = layer(3) x nt(16) x bt(4).
// Block (l, nt, bt): 64 batch rows [bt*64, +64), 64 gate rows (4 gates x 16 n at nt*16).
// Weights persist in LDS (hi/lo).
// Column barrier, sharded 16 ways: sub-counter (bt,nt) gets +1 from the 3 layer
// blocks of that (bt,nt) after each step (release/agent). Before step s every
// column block waits until ALL 16 sub-counters >= 3*s (lanes 0..15 poll in
// parallel, relaxed; then one acquire load). Monotone => skew<=1 => parity
// double-buffer RAW/WAR safe (identical invariant to the single-counter r4).
__global__ void lstm_coop(
    const float* __restrict__ tracks,
    const float* __restrict__ wih0,
    const float* __restrict__ bih0, const float* __restrict__ bhh0,
    const float* __restrict__ bih1, const float* __restrict__ bhh1,
    const float* __restrict__ bih2, const float* __restrict__ bhh2,
    const unsigned short* __restrict__ wre_hi, const unsigned short* __restrict__ wre_lo,
    unsigned short* __restrict__ hb, unsigned int* __restrict__ flags)
{
  extern __shared__ __align__(16) unsigned short smem[];   // [mat][plane][64][WROW]

  const int tid  = threadIdx.x;
  const int l    = blockIdx.x >> 6;
  const int r6   = blockIdx.x & 63;
  const int nt   = r6 & 15, bt = r6 >> 4;
  const int b0   = bt * 64, n0 = nt * 16;
  const int w    = tid >> 6, lane = tid & 63;
  const int m    = lane & 15, q = lane >> 4;

  unsigned int* colflags = flags + bt * 1024;       // 16 sub-counters, 256B apart
  unsigned int* mycnt    = colflags + nt * 64;

  // ---- stage this layer's weight slices into LDS (once) ----
  const int nmats = (l == 0) ? 1 : 2;
  const int gmat0 = (l == 0) ? 0 : (l == 1 ? 1 : 3);
  for (int mi = 0; mi < nmats; ++mi){
    const unsigned short* sh = wre_hi + (gmat0 + mi)*262144 + nt*16384;
    const unsigned short* sl = wre_lo + (gmat0 + mi)*262144 + nt*16384;
    unsigned short* dh = smem + (mi*2 + 0)*64*WROW;
    unsigned short* dl = smem + (mi*2 + 1)*64*WROW;
    for (int c = tid; c < 2048; c += 256){
      int r = c >> 5, off = (c & 31) * 8;
      *(uint4*)(dh + r*WROW + off) = *(const uint4*)(sh + r*256 + off);
      *(uint4*)(dl + r*WROW + off) = *(const uint4*)(sl + r*256 + off);
    }
  }
  __syncthreads();

  // ---- per-lane persistent state ----
  const float* bihL = (l==0) ? bih0 : (l==1) ? bih1 : bih2;
  const float* bhhL = (l==0) ? bhh0 : (l==1) ? bhh1 : bhh2;
  float bsum[4], wx[4][2];
  #pragma unroll
  for (int g = 0; g < 4; ++g){
    int row = g*256 + n0 + m;
    bsum[g] = bihL[row] + bhhL[row];
    wx[g][0] = wih0[row*2 + 0];
    wx[g][1] = wih0[row*2 + 1];
  }
  float cst[4] = {0.f, 0.f, 0.f, 0.f};
  const int arow = b0 + 16*w + m;                  // A-fragment batch row for this lane
  const int woff = m*WROW + q*8;                   // per-lane B-frag LDS offset (shorts)

  for (int s = 0; s < 514; ++s){
    const int t = s - l;
    const bool active = (t >= 0) && (t < 512);

    // ---- x prefetch (read-only, no hazard) before the barrier ----
    float xv0[4], xv1[4];
    if (l == 0 && active){
      #pragma unroll
      for (int r = 0; r < 4; ++r){
        const float* px = tracks + (b0 + 16*w + q*4 + r)*1024 + t*2;
        xv0[r] = px[0]; xv1[r] = px[1];
      }
    }

    // ---- column barrier wait: all 16 sub-counters >= 3*s ----
    if (s > 0){
      if (tid < 64){
        const unsigned int tgt = 3u * (unsigned)s;
        for (;;){
          unsigned int v = tgt;
          if (tid < 16)
            v = __hip_atomic_load(colflags + tid*64, __ATOMIC_RELAXED,
                                  __HIP_MEMORY_SCOPE_AGENT);
          if (__all((int)(v >= tgt))) break;
          __builtin_amdgcn_s_sleep(1);
        }
        if (tid == 0)
          (void)__hip_atomic_load(colflags, __ATOMIC_ACQUIRE,
                                  __HIP_MEMORY_SCOPE_AGENT);
      }
      __syncthreads();
    }

    if (active){
      const int pt = t & 1, pp = pt ^ 1;

      // ---- A fragments from global (LLC-resident h buffers) ----
      bfrag8 a_in[8], a_rec[8];
      {
        const unsigned short* prec = hb + ((pp*3 + l)*256 + arow)*256;
        #pragma unroll
        for (int ks = 0; ks < 8; ++ks)
          a_rec[ks] = *(const bfrag8*)(prec + ks*32 + q*8);
        if (l >= 1){
          const unsigned short* pin = hb + ((pt*3 + (l-1))*256 + arow)*256;
          #pragma unroll
          for (int ks = 0; ks < 8; ++ks)
            a_in[ks] = *(const bfrag8*)(pin + ks*32 + q*8);
        }
      }

      // ---- MFMA: acc[g] over K=256, W split hi/lo ----
      f32x4 acc[4];
      #pragma unroll
      for (int g = 0; g < 4; ++g) acc[g] = (f32x4){0.f,0.f,0.f,0.f};

      { // recurrent mat: slot (l==0 ? 0 : 1)
        const unsigned short* bh = smem + ((l==0?0:2) + 0)*64*WROW + woff;
        const unsigned short* bl = smem + ((l==0?0:2) + 1)*64*WROW + woff;
        #pragma unroll
        for (int ks = 0; ks < 8; ++ks){
          #pragma unroll
          for (int g = 0; g < 4; ++g){
            bfrag8 fh = *(const bfrag8*)(bh + g*16*WROW + ks*32);
            bfrag8 fl = *(const bfrag8*)(bl + g*16*WROW + ks*32);
            acc[g] = __builtin_amdgcn_mfma_f32_16x16x32_bf16(a_rec[ks], fh, acc[g], 0, 0, 0);
            acc[g] = __builtin_amdgcn_mfma_f32_16x16x32_bf16(a_rec[ks], fl, acc[g], 0, 0, 0);
          }
        }
      }
      if (l >= 1){ // input mat: slot 0
        const unsigned short* bh = smem + 0*64*WROW + woff;
        const unsigned short* bl = smem + 1*64*WROW + woff;
        #pragma unroll
        for (int ks = 0; ks < 8; ++ks){
          #pragma unroll
          for (int g = 0; g < 4; ++g){
            bfrag8 fh = *(const bfrag8*)(bh + g*16*WROW + ks*32);
            bfrag8 fl = *(const bfrag8*)(bl + g*16*WROW + ks*32);
            acc[g] = __builtin_amdgcn_mfma_f32_16x16x32_bf16(a_in[ks], fh, acc[g], 0, 0, 0);
            acc[g] = __builtin_amdgcn_mfma_f32_16x16x32_bf16(a_in[ks], fl, acc[g], 0, 0, 0);
          }
        }
      }

      // ---- cell update (gates in registers; c exact fp32) ----
      unsigned short* hout = hb + ((pt*3 + l)*256 + 0)*256;
      #pragma unroll
      for (int r = 0; r < 4; ++r){
        float xi = 0.f, xf = 0.f, xg = 0.f, xo = 0.f;
        if (l == 0){
          xi = xv0[r]*wx[0][0] + xv1[r]*wx[0][1];
          xf = xv0[r]*wx[1][0] + xv1[r]*wx[1][1];
          xg = xv0[r]*wx[2][0] + xv1[r]*wx[2][1];
          xo = xv0[r]*wx[3][0] + xv1[r]*wx[3][1];
        }
        float gi = acc[0][r] + bsum[0] + xi;
        float gf = acc[1][r] + bsum[1] + xf;
        float gg = acc[2][r] + bsum[2] + xg;
        float go = acc[3][r] + bsum[3] + xo;
        float iv = sigf(gi);
        float fv = sigf(gf);
        float gv = tanh_fast(gg);
        float ov = sigf(go);
        cst[r] = fv * cst[r] + iv * gv;
        float hv = ov * tanh_fast(cst[r]);
        hout[(b0 + 16*w + q*4 + r)*256 + n0 + m] = f2bf(hv);
      }
    }

    // ---- arrive: stores drained by syncthreads (vmcnt(0) per wave), then one
    // release-add on this (bt,nt)'s own line (3 contributors -> ~no serialization)
    __syncthreads();
    if (tid == 0)
      __hip_atomic_fetch_add(mycnt, 1u, __ATOMIC_RELEASE, __HIP_MEMORY_SCOPE_AGENT);
  }
}

// out[b] = elu(h2_final[b]) @ W_pred^T + b_pred ; h2 final parity = 511&1 = 1 -> plane 5
__global__ void head_kernel(const unsigned short* __restrict__ hb,
                            const float* __restrict__ wpred,
                            const float* __restrict__ bpred,
                            float* __restrict__ out){
  const int b = blockIdx.x;
  const int k = threadIdx.x;
  const int idx = (5*256 + b)*256 + k;
  float h = bf2f(hb[idx]);
  float e = (h > 0.f) ? h : expm1f(h);
  float v0 = e * wpred[k];
  float v1 = e * wpred[256 + k];
  #pragma unroll
  for (int off = 32; off > 0; off >>= 1){
    v0 += __shfl_down(v0, off, 64);
    v1 += __shfl_down(v1, off, 64);
  }
  __shared__ float r0[4], r1[4];
  int wv = threadIdx.x >> 6, ln = threadIdx.x & 63;
  if (ln == 0){ r0[wv] = v0; r1[wv] = v1; }
  __syncthreads();
  if (threadIdx.x == 0){
    out[b*2 + 0] = r0[0] + r0[1] + r0[2] + r0[3] + bpred[0];
    out[b*2 + 1] = r1[0] + r1[1] + r1[2] + r1[3] + bpred[1];
  }
}

extern "C" void kernel_launch(void* const* d_in, const int* in_sizes, int n_in,
                              void* d_out, int out_size, void* d_ws, size_t ws_size,
                              hipStream_t stream) {
  const float* tracks = (const float*)d_in[0];
  const float* wih0   = (const float*)d_in[1];
  const float* whh0   = (const float*)d_in[2];
  const float* bih0   = (const float*)d_in[3];
  const float* bhh0   = (const float*)d_in[4];
  const float* wih1   = (const float*)d_in[5];
  const float* whh1   = (const float*)d_in[6];
  const float* bih1   = (const float*)d_in[7];
  const float* bhh1   = (const float*)d_in[8];
  const float* wih2   = (const float*)d_in[9];
  const float* whh2   = (const float*)d_in[10];
  const float* bih2   = (const float*)d_in[11];
  const float* bhh2   = (const float*)d_in[12];
  const float* wpred  = (const float*)d_in[13];
  const float* bpred  = (const float*)d_in[14];
  float* out = (float*)d_out;

  char* ws = (char*)d_ws;
  unsigned short* wre_hi = (unsigned short*)(ws);
  unsigned short* wre_lo = (unsigned short*)(ws + WRE_LO_OFF);
  unsigned short* hb     = (unsigned short*)(ws + HB_OFF);
  unsigned int*   flags  = (unsigned int*)(ws + FLAGS_OFF);

  (void)hipFuncSetAttribute((const void*)lstm_coop,
                            hipFuncAttributeMaxDynamicSharedMemorySize, SMEM_BYTES);

  init_reorder<<<5120, 256, 0, stream>>>(whh0, wih1, whh1, wih2, whh2, wre_hi, wre_lo);
  // zero hb (786432 B) + flags (16384 B) = 803 KB -> 50176 uint4
  init_zero<<<197, 256, 0, stream>>>((uint4*)(ws + HB_OFF), 50176);

  void* args[12];
  args[0]  = (void*)&tracks;
  args[1]  = (void*)&wih0;
  args[2]  = (void*)&bih0;
  args[3]  = (void*)&bhh0;
  args[4]  = (void*)&bih1;
  args[5]  = (void*)&bhh1;
  args[6]  = (void*)&bih2;
  args[7]  = (void*)&bhh2;
  args[8]  = (void*)&wre_hi;
  args[9]  = (void*)&wre_lo;
  args[10] = (void*)&hb;
  args[11] = (void*)&flags;
  // cooperative launch kept purely for the all-blocks-co-resident guarantee
  hipLaunchCooperativeKernel((const void*)lstm_coop, dim3(192), dim3(256), args,
                             SMEM_BYTES, stream);

  head_kernel<<<256, 256, 0, stream>>>(hb, wpred, bpred, out);
}

// Round 6
// 3383.439 us; speedup vs baseline: 14.7784x; 1.6798x over previous
//
#include <hip/hip_runtime.h>
#include <math.h>

typedef __attribute__((ext_vector_type(4))) float f32x4;
typedef __attribute__((ext_vector_type(4))) int   i32x4;
typedef __attribute__((ext_vector_type(8))) short bfrag8;   // 8 bf16 = 4 VGPRs

// ---- ws layout (bytes) ----
// wre_hi: 5 mats * 1024 * 256 * 2B = 2621440 @ 0
// wre_lo: same                              @ 2621440
// hb    : 2 par * 3 layers * 256*256 * 2B = 786432 @ 5242880
// flags : 4 columns * 16 subcounters * 64 uints = 16384 B @ 6029312
#define WRE_LO_OFF 2621440
#define HB_OFF     5242880
#define FLAGS_OFF  6029312

// dynamic LDS: [2 mats][2 planes][64 rows][264 bf16]  = 4*64*264*2 = 135168 B
#define WROW 264
#define SMEM_BYTES (4 * 64 * WROW * 2)

__device__ __forceinline__ unsigned short f2bf(float f){
  union { float f; unsigned u; } x; x.f = f;
  unsigned r = x.u + 0x7FFFu + ((x.u >> 16) & 1u);   // RNE
  return (unsigned short)(r >> 16);
}
__device__ __forceinline__ float bf2f(unsigned short s){
  union { unsigned u; float f; } x; x.u = ((unsigned)s) << 16; return x.f;
}
__device__ __forceinline__ float sigf(float x){
  return 1.0f / (1.0f + __expf(-x));
}
__device__ __forceinline__ float tanh_fast(float x){
  x = fminf(fmaxf(x, -15.0f), 15.0f);
  float e = __expf(2.0f * x);
  return (e - 1.0f) / (e + 1.0f);
}

// ---- LLC-direct (coherence-point) access: sc0 sc1 bypasses L1 and L2.
// Cross-XCD visibility without buffer_wbl2 / buffer_inv fences.
__device__ __forceinline__ i32x4 llc_load_b128(const void* p){
  i32x4 r;
  asm volatile("global_load_dwordx4 %0, %1, off sc0 sc1"
               : "=v"(r) : "v"(p) : "memory");
  return r;
}
__device__ __forceinline__ void llc_store_b16(void* p, unsigned short v){
  unsigned int vv = v;
  asm volatile("global_store_short %0, %1, off sc0 sc1"
               : : "v"(p), "v"(vv) : "memory");
}
__device__ __forceinline__ void wait_vm0(){
  asm volatile("s_waitcnt vmcnt(0)" ::: "memory");
}

// Reorder the 5 big weight mats into per-(nt)-contiguous rows, split bf16 hi/lo.
// dest row d in [0,1024): nt=d>>6, g=(d>>4)&3, n=d&15 ; src row = g*256 + nt*16 + n
__global__ void init_reorder(const float* __restrict__ hh0, const float* __restrict__ ih1,
                             const float* __restrict__ hh1, const float* __restrict__ ih2,
                             const float* __restrict__ hh2,
                             unsigned short* __restrict__ wre_hi,
                             unsigned short* __restrict__ wre_lo){
  int e = blockIdx.x * 256 + threadIdx.x;        // 5*2^18 total
  int mat = e >> 18;
  int d   = (e >> 8) & 1023;
  int k   = e & 255;
  int nt = d >> 6, g = (d >> 4) & 3, n = d & 15;
  int src_row = g*256 + nt*16 + n;
  const float* W = (mat==0) ? hh0 : (mat==1) ? ih1 : (mat==2) ? hh1 : (mat==3) ? ih2 : hh2;
  float v = W[src_row*256 + k];
  unsigned short hi = f2bf(v);
  float lo = v - bf2f(hi);
  wre_hi[e] = hi;
  wre_lo[e] = f2bf(lo);
}

__global__ void init_zero(uint4* __restrict__ p, int n16){
  int i = blockIdx.x * 256 + threadIdx.x;
  if (i < n16) p[i] = make_uint4(0u,0u,0u,0u);
}

// Layer-pipelined LSTM. 192 blocks = layer(3) x nt(16) x bt(4).
// Block (l, nt, bt): 64 batch rows [bt*64, +64), 64 gate rows (4 gates x 16 n at nt*16).
// Weights persist in LDS (hi/lo). h lives at the LLC (sc0sc1 direct access).
// Column barrier, sharded 16 ways: sub-counter (bt,nt) gets +1 from the 3 layer
// blocks of that (bt,nt) after each step (RELAXED agent RMW — atomics execute at
// the coherence point). Wait: lanes 0..15 poll the 16 sub-counters until all
// >= 3*s. Ordering chain: h stores (LLC) -> vmcnt(0) -> RMW ; poll-observe ->
// control-dependent LLC loads. No wbl2/inv anywhere. Monotone => skew<=1 =>
// parity double-buffer RAW/WAR safe (same invariant as r4/r5).
__global__ void lstm_coop(
    const float* __restrict__ tracks,
    const float* __restrict__ wih0,
    const float* __restrict__ bih0, const float* __restrict__ bhh0,
    const float* __restrict__ bih1, const float* __restrict__ bhh1,
    const float* __restrict__ bih2, const float* __restrict__ bhh2,
    const unsigned short* __restrict__ wre_hi, const unsigned short* __restrict__ wre_lo,
    unsigned short* __restrict__ hb, unsigned int* __restrict__ flags)
{
  extern __shared__ __align__(16) unsigned short smem[];   // [mat][plane][64][WROW]

  const int tid  = threadIdx.x;
  const int l    = blockIdx.x >> 6;
  const int r6   = blockIdx.x & 63;
  const int nt   = r6 & 15, bt = r6 >> 4;
  const int b0   = bt * 64, n0 = nt * 16;
  const int w    = tid >> 6, lane = tid & 63;
  const int m    = lane & 15, q = lane >> 4;

  unsigned int* colflags = flags + bt * 1024;       // 16 sub-counters, 256B apart
  unsigned int* mycnt    = colflags + nt * 64;

  // ---- stage this layer's weight slices into LDS (once) ----
  const int nmats = (l == 0) ? 1 : 2;
  const int gmat0 = (l == 0) ? 0 : (l == 1 ? 1 : 3);
  for (int mi = 0; mi < nmats; ++mi){
    const unsigned short* sh = wre_hi + (gmat0 + mi)*262144 + nt*16384;
    const unsigned short* sl = wre_lo + (gmat0 + mi)*262144 + nt*16384;
    unsigned short* dh = smem + (mi*2 + 0)*64*WROW;
    unsigned short* dl = smem + (mi*2 + 1)*64*WROW;
    for (int c = tid; c < 2048; c += 256){
      int r = c >> 5, off = (c & 31) * 8;
      *(uint4*)(dh + r*WROW + off) = *(const uint4*)(sh + r*256 + off);
      *(uint4*)(dl + r*WROW + off) = *(const uint4*)(sl + r*256 + off);
    }
  }
  __syncthreads();

  // ---- per-lane persistent state ----
  const float* bihL = (l==0) ? bih0 : (l==1) ? bih1 : bih2;
  const float* bhhL = (l==0) ? bhh0 : (l==1) ? bhh1 : bhh2;
  float bsum[4], wx[4][2];
  #pragma unroll
  for (int g = 0; g < 4; ++g){
    int row = g*256 + n0 + m;
    bsum[g] = bihL[row] + bhhL[row];
    wx[g][0] = wih0[row*2 + 0];
    wx[g][1] = wih0[row*2 + 1];
  }
  float cst[4] = {0.f, 0.f, 0.f, 0.f};
  const int arow = b0 + 16*w + m;                  // A-fragment batch row for this lane
  const int woff = m*WROW + q*8;                   // per-lane B-frag LDS offset (shorts)

  for (int s = 0; s < 514; ++s){
    const int t = s - l;
    const bool active = (t >= 0) && (t < 512);

    // ---- x prefetch (read-only, no hazard) before the barrier ----
    float xv0[4], xv1[4];
    if (l == 0 && active){
      #pragma unroll
      for (int r = 0; r < 4; ++r){
        const float* px = tracks + (b0 + 16*w + q*4 + r)*1024 + t*2;
        xv0[r] = px[0]; xv1[r] = px[1];
      }
    }

    // ---- column barrier wait: all 16 sub-counters >= 3*s (no acquire fence;
    // h is read LLC-direct, so nothing stale can be cached) ----
    if (s > 0){
      if (tid < 64){
        const unsigned int tgt = 3u * (unsigned)s;
        for (;;){
          unsigned int v = tgt;
          if (tid < 16)
            v = __hip_atomic_load(colflags + tid*64, __ATOMIC_RELAXED,
                                  __HIP_MEMORY_SCOPE_AGENT);
          if (__all((int)(v >= tgt))) break;
          __builtin_amdgcn_s_sleep(1);
        }
      }
      __syncthreads();
    }

    if (active){
      const int pt = t & 1, pp = pt ^ 1;

      // ---- A fragments: LLC-direct loads (issued after barrier; control dep) ----
      i32x4 ar_raw[8], ai_raw[8];
      {
        const unsigned short* prec = hb + ((pp*3 + l)*256 + arow)*256 + q*8;
        #pragma unroll
        for (int ks = 0; ks < 8; ++ks)
          ar_raw[ks] = llc_load_b128(prec + ks*32);
        if (l >= 1){
          const unsigned short* pin = hb + ((pt*3 + (l-1))*256 + arow)*256 + q*8;
          #pragma unroll
          for (int ks = 0; ks < 8; ++ks)
            ai_raw[ks] = llc_load_b128(pin + ks*32);
        }
      }
      wait_vm0();

      // ---- MFMA: acc[g] over K=256, W split hi/lo ----
      f32x4 acc[4];
      #pragma unroll
      for (int g = 0; g < 4; ++g) acc[g] = (f32x4){0.f,0.f,0.f,0.f};

      { // recurrent mat: slot (l==0 ? 0 : 1)
        const unsigned short* bh = smem + ((l==0?0:2) + 0)*64*WROW + woff;
        const unsigned short* bl = smem + ((l==0?0:2) + 1)*64*WROW + woff;
        #pragma unroll
        for (int ks = 0; ks < 8; ++ks){
          bfrag8 a = __builtin_bit_cast(bfrag8, ar_raw[ks]);
          #pragma unroll
          for (int g = 0; g < 4; ++g){
            bfrag8 fh = *(const bfrag8*)(bh + g*16*WROW + ks*32);
            bfrag8 fl = *(const bfrag8*)(bl + g*16*WROW + ks*32);
            acc[g] = __builtin_amdgcn_mfma_f32_16x16x32_bf16(a, fh, acc[g], 0, 0, 0);
            acc[g] = __builtin_amdgcn_mfma_f32_16x16x32_bf16(a, fl, acc[g], 0, 0, 0);
          }
        }
      }
      if (l >= 1){ // input mat: slot 0
        const unsigned short* bh = smem + 0*64*WROW + woff;
        const unsigned short* bl = smem + 1*64*WROW + woff;
        #pragma unroll
        for (int ks = 0; ks < 8; ++ks){
          bfrag8 a = __builtin_bit_cast(bfrag8, ai_raw[ks]);
          #pragma unroll
          for (int g = 0; g < 4; ++g){
            bfrag8 fh = *(const bfrag8*)(bh + g*16*WROW + ks*32);
            bfrag8 fl = *(const bfrag8*)(bl + g*16*WROW + ks*32);
            acc[g] = __builtin_amdgcn_mfma_f32_16x16x32_bf16(a, fh, acc[g], 0, 0, 0);
            acc[g] = __builtin_amdgcn_mfma_f32_16x16x32_bf16(a, fl, acc[g], 0, 0, 0);
          }
        }
      }

      // ---- cell update (gates in registers; c exact fp32); h stores LLC-direct ----
      unsigned short* hout = hb + ((pt*3 + l)*256 + 0)*256;
      #pragma unroll
      for (int r = 0; r < 4; ++r){
        float xi = 0.f, xf = 0.f, xg = 0.f, xo = 0.f;
        if (l == 0){
          xi = xv0[r]*wx[0][0] + xv1[r]*wx[0][1];
          xf = xv0[r]*wx[1][0] + xv1[r]*wx[1][1];
          xg = xv0[r]*wx[2][0] + xv1[r]*wx[2][1];
          xo = xv0[r]*wx[3][0] + xv1[r]*wx[3][1];
        }
        float gi = acc[0][r] + bsum[0] + xi;
        float gf = acc[1][r] + bsum[1] + xf;
        float gg = acc[2][r] + bsum[2] + xg;
        float go = acc[3][r] + bsum[3] + xo;
        float iv = sigf(gi);
        float fv = sigf(gf);
        float gv = tanh_fast(gg);
        float ov = sigf(go);
        cst[r] = fv * cst[r] + iv * gv;
        float hv = ov * tanh_fast(cst[r]);
        llc_store_b16(&hout[(b0 + 16*w + q*4 + r)*256 + n0 + m], f2bf(hv));
      }
    }

    // ---- arrive: each thread drains its own LLC stores, block barrier orders
    // all waves, then one RELAXED release-free RMW on this (bt,nt)'s line ----
    wait_vm0();
    __syncthreads();
    if (tid == 0)
      __hip_atomic_fetch_add(mycnt, 1u, __ATOMIC_RELAXED, __HIP_MEMORY_SCOPE_AGENT);
  }
}

// out[b] = elu(h2_final[b]) @ W_pred^T + b_pred ; h2 final parity = 511&1 = 1 -> plane 5
__global__ void head_kernel(const unsigned short* __restrict__ hb,
                            const float* __restrict__ wpred,
                            const float* __restrict__ bpred,
                            float* __restrict__ out){
  const int b = blockIdx.x;
  const int k = threadIdx.x;
  const int idx = (5*256 + b)*256 + k;
  float h = bf2f(hb[idx]);
  float e = (h > 0.f) ? h : expm1f(h);
  float v0 = e * wpred[k];
  float v1 = e * wpred[256 + k];
  #pragma unroll
  for (int off = 32; off > 0; off >>= 1){
    v0 += __shfl_down(v0, off, 64);
    v1 += __shfl_down(v1, off, 64);
  }
  __shared__ float r0[4], r1[4];
  int wv = threadIdx.x >> 6, ln = threadIdx.x & 63;
  if (ln == 0){ r0[wv] = v0; r1[wv] = v1; }
  __syncthreads();
  if (threadIdx.x == 0){
    out[b*2 + 0] = r0[0] + r0[1] + r0[2] + r0[3] + bpred[0];
    out[b*2 + 1] = r1[0] + r1[1] + r1[2] + r1[3] + bpred[1];
  }
}

extern "C" void kernel_launch(void* const* d_in, const int* in_sizes, int n_in,
                              void* d_out, int out_size, void* d_ws, size_t ws_size,
                              hipStream_t stream) {
  const float* tracks = (const float*)d_in[0];
  const float* wih0   = (const float*)d_in[1];
  const float* whh0   = (const float*)d_in[2];
  const float* bih0   = (const float*)d_in[3];
  const float* bhh0   = (const float*)d_in[4];
  const float* wih1   = (const float*)d_in[5];
  const float* whh1   = (const float*)d_in[6];
  const float* bih1   = (const float*)d_in[7];
  const float* bhh1   = (const float*)d_in[8];
  const float* wih2   = (const float*)d_in[9];
  const float* whh2   = (const float*)d_in[10];
  const float* bih2   = (const float*)d_in[11];
  const float* bhh2   = (const float*)d_in[12];
  const float* wpred  = (const float*)d_in[13];
  const float* bpred  = (const float*)d_in[14];
  float* out = (float*)d_out;

  char* ws = (char*)d_ws;
  unsigned short* wre_hi = (unsigned short*)(ws);
  unsigned short* wre_lo = (unsigned short*)(ws + WRE_LO_OFF);
  unsigned short* hb     = (unsigned short*)(ws + HB_OFF);
  unsigned int*   flags  = (unsigned int*)(ws + FLAGS_OFF);

  (void)hipFuncSetAttribute((const void*)lstm_coop,
                            hipFuncAttributeMaxDynamicSharedMemorySize, SMEM_BYTES);

  init_reorder<<<5120, 256, 0, stream>>>(whh0, wih1, whh1, wih2, whh2, wre_hi, wre_lo);
  // zero hb (786432 B) + flags (16384 B) -> 50176 uint4
  init_zero<<<197, 256, 0, stream>>>((uint4*)(ws + HB_OFF), 50176);

  void* args[12];
  args[0]  = (void*)&tracks;
  args[1]  = (void*)&wih0;
  args[2]  = (void*)&bih0;
  args[3]  = (void*)&bhh0;
  args[4]  = (void*)&bih1;
  args[5]  = (void*)&bhh1;
  args[6]  = (void*)&bih2;
  args[7]  = (void*)&bhh2;
  args[8]  = (void*)&wre_hi;
  args[9]  = (void*)&wre_lo;
  args[10] = (void*)&hb;
  args[11] = (void*)&flags;
  // cooperative launch kept purely for the all-blocks-co-resident guarantee
  hipLaunchCooperativeKernel((const void*)lstm_coop, dim3(192), dim3(256), args,
                             SMEM_BYTES, stream);

  head_kernel<<<256, 256, 0, stream>>>(hb, wpred, bpred, out);
}